// Round 2
// baseline (176.549 us; speedup 1.0000x reference)
//
#include <hip/hip_runtime.h>
#include <hip/hip_bf16.h>

#define BATCH 4096
#define NROWS 8192
#define DIM 256
#define CS_COUNT 16                       // column splits
#define COLS_PER_CS (NROWS / CS_COUNT)    // 512
#define ROWS_PER_BLOCK 128
#define ROWS_PER_WAVE 32

// zn scale c with c^2 = 2*log2(e): sim_scaled = c^2*cos = 2*log2e*cos,
// so exp2(sim_scaled) = e^{2 cos} directly (one v_exp_f32, no mul).
#define ZN_SCALE 1.698643600577466f       // sqrt(2.8853900817779268)
#define LN2F 0.6931471805599453f

typedef __attribute__((ext_vector_type(4))) float f32x4;
typedef __attribute__((ext_vector_type(8))) short short8;

#if defined(__has_builtin)
#if __has_builtin(__builtin_amdgcn_exp2f)
#define EXP2F(x) __builtin_amdgcn_exp2f(x)
#endif
#endif
#ifndef EXP2F
#define EXP2F(x) __expf(LN2F * (x))
#endif

static __device__ __forceinline__ unsigned short f2bf(float x) {
    __hip_bfloat16 h = __float2bfloat16(x);
    return *reinterpret_cast<unsigned short*>(&h);
}
static __device__ __forceinline__ float bf2f(unsigned short u) {
    union { unsigned int i; float f; } x;
    x.i = ((unsigned int)u) << 16;
    return x.f;
}

// ---------------------------------------------------------------------------
// Kernel A: concat + L2-normalize + scale, write row-major (zn) AND
// MFMA-fragment-packed (pk) layouts.
// Packed granule for (row, e): g = ((row>>4)*8 + (e>>5))*64 + ((e&31)>>3)*16
//                                  + (row&15), element j = e&7.
// One wave per row: lane l holds elements 4l..4l+3 (one granule half).
// ---------------------------------------------------------------------------
__global__ void normalize_kernel(const float* __restrict__ z_i,
                                 const float* __restrict__ z_j,
                                 unsigned short* __restrict__ zn,
                                 unsigned short* __restrict__ pk) {
    int wid  = (blockIdx.x * blockDim.x + threadIdx.x) >> 6;   // row
    int lane = threadIdx.x & 63;
    if (wid >= NROWS) return;
    const float* src = (wid < BATCH) ? (z_i + (size_t)wid * DIM)
                                     : (z_j + (size_t)(wid - BATCH) * DIM);
    float4 v = reinterpret_cast<const float4*>(src)[lane];
    float ss = v.x * v.x + v.y * v.y + v.z * v.z + v.w * v.w;
#pragma unroll
    for (int m = 1; m < 64; m <<= 1) ss += __shfl_xor(ss, m);
    float inv = ZN_SCALE / fmaxf(sqrtf(ss), 1e-8f);
    ushort4 o;
    o.x = f2bf(v.x * inv);
    o.y = f2bf(v.y * inv);
    o.z = f2bf(v.z * inv);
    o.w = f2bf(v.w * inv);
    reinterpret_cast<ushort4*>(zn + (size_t)wid * DIM)[lane] = o;
    size_t g = ((size_t)(wid >> 4) * 8 + (lane >> 3)) * 64
             + ((lane & 7) >> 1) * 16 + (wid & 15);
    *reinterpret_cast<ushort4*>(pk + g * 8 + (lane & 1) * 4) = o;
}

// ---------------------------------------------------------------------------
// Kernel B: fused sim-GEMM + sum-of-exp per row.
// Grid: 1024 blocks = 64 row-blocks x 16 col-splits. Block = 4 waves.
// Wave owns 32 rows (2 MFMA row-tiles); A and B fragments both come from the
// packed layout -> every fragment load is one coalesced 1KB dwordx4 stream.
// ---------------------------------------------------------------------------
__device__ __forceinline__ void load_bfrags(const unsigned short* __restrict__ pk,
                                            int c, int lane, short8* b) {
#pragma unroll
    for (int kk = 0; kk < 8; ++kk)
        b[kk] = *reinterpret_cast<const short8*>(
            pk + (((size_t)(c >> 4) * 8 + kk) * 64 + lane) * 8);
}

__device__ __forceinline__ void compute_tile(const short8 (&af)[2][8],
                                             const short8* bf,
                                             int c, int row0, int lr, int lk,
                                             float (&dacc)[2][4]) {
    f32x4 acc0 = {0.f, 0.f, 0.f, 0.f};
    f32x4 acc1 = {0.f, 0.f, 0.f, 0.f};
#pragma unroll
    for (int kk = 0; kk < 8; ++kk) {
        acc0 = __builtin_amdgcn_mfma_f32_16x16x32_bf16(af[0][kk], bf[kk], acc0, 0, 0, 0);
        acc1 = __builtin_amdgcn_mfma_f32_16x16x32_bf16(af[1][kk], bf[kk], acc1, 0, 0, 0);
    }
    int col = c + lr;              // C/D: col = lane&15, row = (lane>>4)*4 + j
    if (c == row0) {               // uniform branch: diagonal crosses this tile
#pragma unroll
        for (int j = 0; j < 4; ++j) {
            float e = EXP2F(acc0[j]);
            if (col == row0 + lk * 4 + j) e = 0.0f;   // exclude diagonal
            dacc[0][j] += e;
        }
    } else {
#pragma unroll
        for (int j = 0; j < 4; ++j) dacc[0][j] += EXP2F(acc0[j]);
    }
    if (c == row0 + 16) {
#pragma unroll
        for (int j = 0; j < 4; ++j) {
            float e = EXP2F(acc1[j]);
            if (col == row0 + 16 + lk * 4 + j) e = 0.0f;
            dacc[1][j] += e;
        }
    } else {
#pragma unroll
        for (int j = 0; j < 4; ++j) dacc[1][j] += EXP2F(acc1[j]);
    }
}

__global__ __launch_bounds__(256, 4)
void simloss_kernel(const unsigned short* __restrict__ pk,
                    float* __restrict__ part /* [CS_COUNT][NROWS] */) {
    int wave = threadIdx.x >> 6;
    int lane = threadIdx.x & 63;
    int lr = lane & 15;            // fragment row / col index
    int lk = lane >> 4;            // k-subgroup
    int rb = blockIdx.x & 63;
    int cs = blockIdx.x >> 6;
    int row0 = rb * ROWS_PER_BLOCK + wave * ROWS_PER_WAVE;
    int c0 = cs * COLS_PER_CS;

    // A fragments: 2 row-tiles x 8 k-frags from packed layout (coalesced)
    short8 af[2][8];
#pragma unroll
    for (int t = 0; t < 2; ++t)
#pragma unroll
        for (int kk = 0; kk < 8; ++kk)
            af[t][kk] = *reinterpret_cast<const short8*>(
                pk + ((((size_t)(row0 >> 4) + t) * 8 + kk) * 64 + lane) * 8);

    float dacc[2][4] = {{0.f, 0.f, 0.f, 0.f}, {0.f, 0.f, 0.f, 0.f}};

    short8 bufA[8], bufB[8];
    load_bfrags(pk, c0, lane, bufA);
#pragma unroll 1
    for (int ct = 0; ct < COLS_PER_CS / 16; ct += 2) {
        int cA = c0 + ct * 16;
        int cB = cA + 16;
        load_bfrags(pk, cB, lane, bufB);                 // prefetch odd
        compute_tile(af, bufA, cA, row0, lr, lk, dacc);
        if (ct + 2 < COLS_PER_CS / 16)
            load_bfrags(pk, cA + 32, lane, bufA);        // prefetch next even
        compute_tile(af, bufB, cB, row0, lr, lk, dacc);
    }

    // reduce dacc across the 16 lanes sharing the same rows (lr dimension)
#pragma unroll
    for (int t = 0; t < 2; ++t)
#pragma unroll
        for (int j = 0; j < 4; ++j) {
            float v = dacc[t][j];
            v += __shfl_xor(v, 1);
            v += __shfl_xor(v, 2);
            v += __shfl_xor(v, 4);
            v += __shfl_xor(v, 8);
            if (lr == 0)
                part[(size_t)cs * NROWS + row0 + t * 16 + lk * 4 + j] = v;
        }
}

// ---------------------------------------------------------------------------
// Kernel C: per-row loss: log(sum of partials) - (pos_dot)*ln2
// (zn is scaled so dot = 2*log2e*cos; 2*cos = dot*ln2)
// ---------------------------------------------------------------------------
__global__ void rowloss_kernel(const unsigned short* __restrict__ zn,
                               const float* __restrict__ part,
                               float* __restrict__ cpart) {
    int wave = threadIdx.x >> 6;
    int lane = threadIdx.x & 63;
    float wsum = 0.0f;
#pragma unroll 1
    for (int it = 0; it < 8; ++it) {
        int r = blockIdx.x * 32 + wave * 8 + it;
        ushort4 za = reinterpret_cast<const ushort4*>(zn + (size_t)r * DIM)[lane];
        ushort4 zb = reinterpret_cast<const ushort4*>(zn + (size_t)(r ^ BATCH) * DIM)[lane];
        float dot = bf2f(za.x) * bf2f(zb.x) + bf2f(za.y) * bf2f(zb.y) +
                    bf2f(za.z) * bf2f(zb.z) + bf2f(za.w) * bf2f(zb.w);
#pragma unroll
        for (int m = 1; m < 64; m <<= 1) dot += __shfl_xor(dot, m);
        float den = (lane < CS_COUNT) ? part[(size_t)lane * NROWS + r] : 0.0f;
        den += __shfl_xor(den, 8);
        den += __shfl_xor(den, 4);
        den += __shfl_xor(den, 2);
        den += __shfl_xor(den, 1);
        if (lane == 0) wsum += logf(den) - dot * LN2F;
    }
    __shared__ float red[4];
    if (lane == 0) red[wave] = wsum;
    __syncthreads();
    if (threadIdx.x == 0)
        cpart[blockIdx.x] = red[0] + red[1] + red[2] + red[3];
}

// ---------------------------------------------------------------------------
// Kernel D: final reduction of 256 block partials -> scalar loss / n
// ---------------------------------------------------------------------------
__global__ void final_kernel(const float* __restrict__ cpart,
                             float* __restrict__ out) {
    int lane = threadIdx.x & 63;
    int wave = threadIdx.x >> 6;
    double v = (double)cpart[threadIdx.x];
#pragma unroll
    for (int m = 1; m < 64; m <<= 1) v += __shfl_xor(v, m);
    __shared__ double red[4];
    if (lane == 0) red[wave] = v;
    __syncthreads();
    if (threadIdx.x == 0)
        out[0] = (float)((red[0] + red[1] + red[2] + red[3]) / (double)NROWS);
}

// ---------------------------------------------------------------------------
extern "C" void kernel_launch(void* const* d_in, const int* in_sizes, int n_in,
                              void* d_out, int out_size, void* d_ws, size_t ws_size,
                              hipStream_t stream) {
    const float* z_i = (const float*)d_in[0];
    const float* z_j = (const float*)d_in[1];
    float* out = (float*)d_out;
    char* ws = (char*)d_ws;

    unsigned short* zn = (unsigned short*)ws;                              // 4 MB
    unsigned short* pk = (unsigned short*)(ws + (size_t)NROWS * DIM * 2);  // 4 MB
    float* part  = (float*)(ws + 2 * (size_t)NROWS * DIM * 2);             // 512 KB
    float* cpart = (float*)(ws + 2 * (size_t)NROWS * DIM * 2
                               + (size_t)CS_COUNT * NROWS * 4);

    normalize_kernel<<<NROWS / 4, 256, 0, stream>>>(z_i, z_j, zn, pk);
    simloss_kernel<<<(NROWS / ROWS_PER_BLOCK) * CS_COUNT, 256, 0, stream>>>(pk, part);
    rowloss_kernel<<<NROWS / 32, 256, 0, stream>>>(zn, part, cpart);
    final_kernel<<<1, 256, 0, stream>>>(cpart, out);
}

// Round 4
// 65.305 us; speedup vs baseline: 2.7034x; 2.7034x over previous
//
#include <hip/hip_runtime.h>
#include <hip/hip_bf16.h>

#define BATCH 4096
#define NROWS 8192
#define DIM 256
#define CS_COUNT 16                       // column splits
#define COLS_PER_CS (NROWS / CS_COUNT)    // 512
#define ROWS_PER_BLOCK 128
#define NPART 32                          // CS_COUNT * 2 column-half partials

// zn scale c with c^2 = 2*log2(e): sim_scaled = c^2*cos = 2*log2e*cos,
// so exp2(sim_scaled) = e^{2 cos} directly.
#define ZN_SCALE 1.698643600577466f       // sqrt(2.8853900817779268)
#define LN2F 0.6931471805599453f

typedef __attribute__((ext_vector_type(4))) float f32x4;
typedef __attribute__((ext_vector_type(8))) short short8;

#if defined(__has_builtin)
#if __has_builtin(__builtin_amdgcn_exp2f)
#define EXP2F(x) __builtin_amdgcn_exp2f(x)
#endif
#endif
#ifndef EXP2F
#define EXP2F(x) __expf(LN2F * (x))
#endif

static __device__ __forceinline__ unsigned short f2bf(float x) {
    __hip_bfloat16 h = __float2bfloat16(x);
    return *reinterpret_cast<unsigned short*>(&h);
}
static __device__ __forceinline__ float bf2f(unsigned short u) {
    union { unsigned int i; float f; } x;
    x.i = ((unsigned int)u) << 16;
    return x.f;
}

// ---------------------------------------------------------------------------
// Kernel A: concat + L2-normalize + scale, write row-major (zn) AND
// MFMA-fragment-packed (pk) layouts.
// pk: element (row r, dim e) lives at granule g*8 + (e&7), where
//     g = ((r>>4)*8 + (e>>5))*64 + ((e&31)>>3)*16 + (r&15)
// i.e. one 1KB granule-row per (16-row x 32-k) MFMA fragment, in lane order.
// ---------------------------------------------------------------------------
__global__ void normalize_kernel(const float* __restrict__ z_i,
                                 const float* __restrict__ z_j,
                                 unsigned short* __restrict__ zn,
                                 unsigned short* __restrict__ pk) {
    int wid  = (blockIdx.x * blockDim.x + threadIdx.x) >> 6;   // row
    int lane = threadIdx.x & 63;
    if (wid >= NROWS) return;
    const float* src = (wid < BATCH) ? (z_i + (size_t)wid * DIM)
                                     : (z_j + (size_t)(wid - BATCH) * DIM);
    float4 v = reinterpret_cast<const float4*>(src)[lane];
    float ss = v.x * v.x + v.y * v.y + v.z * v.z + v.w * v.w;
#pragma unroll
    for (int m = 1; m < 64; m <<= 1) ss += __shfl_xor(ss, m);
    float inv = ZN_SCALE / fmaxf(sqrtf(ss), 1e-8f);
    ushort4 o;
    o.x = f2bf(v.x * inv);
    o.y = f2bf(v.y * inv);
    o.z = f2bf(v.z * inv);
    o.w = f2bf(v.w * inv);
    reinterpret_cast<ushort4*>(zn + (size_t)wid * DIM)[lane] = o;
    size_t g = ((size_t)(wid >> 4) * 8 + (lane >> 3)) * 64
             + ((lane & 7) >> 1) * 16 + (wid & 15);
    *reinterpret_cast<ushort4*>(pk + g * 8 + (lane & 1) * 4) = o;
}

// ---------------------------------------------------------------------------
// Kernel B: fused sim-GEMM + sum-of-exp per row (m97-style LDS pipeline).
// Grid: 1024 blocks = 64 row-blocks x 16 col-splits. Block = 4 waves (2x2).
// Block tile: 128 rows x 512 cols, processed as 4 col-tiles of 128.
// Per K-step (BK=64): A[128x64] + B[128x64] staged to LDS (double-buffered,
// 64 KB) via global_load_lds from pk (linear dest, 16B/lane).
// Wave (wr=wave>>1, wc=wave&1) computes a 64x64 output quadrant: acc[4][4],
// consumed by the exp2 epilogue per col-tile; per-row partial goes to
// part[cs*2 + wc] (column-half-distinct => no cross-wave write collision).
// ---------------------------------------------------------------------------
typedef const __attribute__((address_space(1))) unsigned int g_u32;
typedef __attribute__((address_space(3))) unsigned int l_u32;

__device__ __forceinline__ void stage_step(const char* __restrict__ pkb,
                                           char* lds, int wave, int lane,
                                           int rb, int cs, int s, int buf) {
    int ct = s >> 2, ks = s & 3;
#pragma unroll
    for (int i = 0; i < 8; ++i) {
        int id  = wave * 8 + i;
        int isB = id >> 4;               // waves 0,1 stage A; 2,3 stage B
        int rtl = (id >> 1) & 7;         // local row-tile 0..7
        int kf  = id & 1;                // which of the 2 k-frags in BK=64
        int rtbase = isB ? (cs * 32 + ct * 8) : (rb * 8);
        size_t grow = (size_t)(rtbase + rtl) * 8 + ks * 2 + kf;
        const char* src = pkb + grow * 1024 + (size_t)lane * 16;
        char* dst = lds + buf * 32768 + isB * 16384 + (rtl * 2 + kf) * 1024;
        __builtin_amdgcn_global_load_lds((g_u32*)src, (l_u32*)dst, 16, 0, 0);
    }
}

__global__ __launch_bounds__(256, 2)
void simloss_kernel(const unsigned short* __restrict__ pk,
                    float* __restrict__ part /* [NPART][NROWS] */) {
    __shared__ __attribute__((aligned(16))) unsigned char lds[65536];
    int wave = threadIdx.x >> 6;
    int lane = threadIdx.x & 63;
    int lr = lane & 15;                  // output col within 16-frag
    int lk = lane >> 4;                  // output row group
    int rb = blockIdx.x & 63;
    int cs = blockIdx.x >> 6;
    int wr4 = (wave >> 1) * 4;           // A local row-tile base
    int wc4 = (wave & 1) * 4;            // B local row-tile base
    int R0 = rb * ROWS_PER_BLOCK + (wave >> 1) * 64;
    const char* pkb = (const char*)pk;

    f32x4 acc[4][4];
#pragma unroll
    for (int m = 0; m < 4; ++m)
#pragma unroll
        for (int n = 0; n < 4; ++n) acc[m][n] = (f32x4){0.f, 0.f, 0.f, 0.f};
    float dacc[4][4];
#pragma unroll
    for (int m = 0; m < 4; ++m)
#pragma unroll
        for (int j = 0; j < 4; ++j) dacc[m][j] = 0.f;

    stage_step(pkb, (char*)lds, wave, lane, rb, cs, 0, 0);

#pragma unroll 1
    for (int s = 0; s < 16; ++s) {
        int buf = s & 1;
        if (s < 15) {
            stage_step(pkb, (char*)lds, wave, lane, rb, cs, s + 1, buf ^ 1);
            asm volatile("s_waitcnt vmcnt(8)" ::: "memory");
        } else {
            asm volatile("s_waitcnt vmcnt(0)" ::: "memory");
        }
        __builtin_amdgcn_s_barrier();

        const unsigned short* Ab = (const unsigned short*)(lds + buf * 32768);
        const unsigned short* Bb = (const unsigned short*)(lds + buf * 32768 + 16384);
#pragma unroll
        for (int kf = 0; kf < 2; ++kf) {
            short8 a[4], b[4];
#pragma unroll
            for (int m = 0; m < 4; ++m)
                a[m] = *(const short8*)(Ab + ((wr4 + m) * 2 + kf) * 512 + lane * 8);
#pragma unroll
            for (int n = 0; n < 4; ++n)
                b[n] = *(const short8*)(Bb + ((wc4 + n) * 2 + kf) * 512 + lane * 8);
#pragma unroll
            for (int m = 0; m < 4; ++m)
#pragma unroll
                for (int n = 0; n < 4; ++n)
                    acc[m][n] = __builtin_amdgcn_mfma_f32_16x16x32_bf16(
                        a[m], b[n], acc[m][n], 0, 0, 0);
        }

        if ((s & 3) == 3) {              // col-tile finished: exp2 epilogue
            int ct = s >> 2;
            int Ct = cs * COLS_PER_CS + ct * 128 + (wave & 1) * 64;
#pragma unroll
            for (int m = 0; m < 4; ++m) {
                int rbase = R0 + m * 16;
#pragma unroll
                for (int n = 0; n < 4; ++n) {
                    if (rbase == Ct + n * 16) {        // diagonal tile (uniform)
#pragma unroll
                        for (int j = 0; j < 4; ++j) {
                            float e = EXP2F(acc[m][n][j]);
                            if (lr == lk * 4 + j) e = 0.0f;
                            dacc[m][j] += e;
                        }
                    } else {
#pragma unroll
                        for (int j = 0; j < 4; ++j)
                            dacc[m][j] += EXP2F(acc[m][n][j]);
                    }
                    acc[m][n] = (f32x4){0.f, 0.f, 0.f, 0.f};
                }
            }
        }
        asm volatile("" ::: "memory");
        __builtin_amdgcn_s_barrier();
    }

    // reduce over the 16 output-col lanes (lr); lanes lr==0 hold row sums.
    // Each wave writes its own column-half slot: no collision between the
    // two waves sharing the same output rows.
#pragma unroll
    for (int m = 0; m < 4; ++m)
#pragma unroll
        for (int j = 0; j < 4; ++j) {
            float v = dacc[m][j];
            v += __shfl_xor(v, 1);
            v += __shfl_xor(v, 2);
            v += __shfl_xor(v, 4);
            v += __shfl_xor(v, 8);
            if (lr == 0)
                part[(size_t)(cs * 2 + (wave & 1)) * NROWS
                     + R0 + m * 16 + lk * 4 + j] = v;
        }
}

// ---------------------------------------------------------------------------
// Kernel C: per-row loss: log(sum of 32 partials) - pos_dot*ln2
// (zn is scaled so dot = 2*log2e*cos; 2*cos = dot*ln2)
// ---------------------------------------------------------------------------
__global__ void rowloss_kernel(const unsigned short* __restrict__ zn,
                               const float* __restrict__ part,
                               float* __restrict__ cpart) {
    int wave = threadIdx.x >> 6;
    int lane = threadIdx.x & 63;
    float wsum = 0.0f;
#pragma unroll 1
    for (int it = 0; it < 8; ++it) {
        int r = blockIdx.x * 32 + wave * 8 + it;
        ushort4 za = reinterpret_cast<const ushort4*>(zn + (size_t)r * DIM)[lane];
        ushort4 zb = reinterpret_cast<const ushort4*>(zn + (size_t)(r ^ BATCH) * DIM)[lane];
        float dot = bf2f(za.x) * bf2f(zb.x) + bf2f(za.y) * bf2f(zb.y) +
                    bf2f(za.z) * bf2f(zb.z) + bf2f(za.w) * bf2f(zb.w);
#pragma unroll
        for (int m = 1; m < 64; m <<= 1) dot += __shfl_xor(dot, m);
        float den = (lane < NPART) ? part[(size_t)lane * NROWS + r] : 0.0f;
        den += __shfl_xor(den, 16);
        den += __shfl_xor(den, 8);
        den += __shfl_xor(den, 4);
        den += __shfl_xor(den, 2);
        den += __shfl_xor(den, 1);
        if (lane == 0) wsum += logf(den) - dot * LN2F;
    }
    __shared__ float red[4];
    if (lane == 0) red[wave] = wsum;
    __syncthreads();
    if (threadIdx.x == 0)
        cpart[blockIdx.x] = red[0] + red[1] + red[2] + red[3];
}

// ---------------------------------------------------------------------------
// Kernel D: final reduction of 256 block partials -> scalar loss / n
// ---------------------------------------------------------------------------
__global__ void final_kernel(const float* __restrict__ cpart,
                             float* __restrict__ out) {
    int lane = threadIdx.x & 63;
    int wave = threadIdx.x >> 6;
    double v = (double)cpart[threadIdx.x];
#pragma unroll
    for (int m = 1; m < 64; m <<= 1) v += __shfl_xor(v, m);
    __shared__ double red[4];
    if (lane == 0) red[wave] = v;
    __syncthreads();
    if (threadIdx.x == 0)
        out[0] = (float)((red[0] + red[1] + red[2] + red[3]) / (double)NROWS);
}

// ---------------------------------------------------------------------------
extern "C" void kernel_launch(void* const* d_in, const int* in_sizes, int n_in,
                              void* d_out, int out_size, void* d_ws, size_t ws_size,
                              hipStream_t stream) {
    const float* z_i = (const float*)d_in[0];
    const float* z_j = (const float*)d_in[1];
    float* out = (float*)d_out;
    char* ws = (char*)d_ws;

    unsigned short* zn = (unsigned short*)ws;                              // 4 MB
    unsigned short* pk = (unsigned short*)(ws + (size_t)NROWS * DIM * 2);  // 4 MB
    float* part  = (float*)(ws + 2 * (size_t)NROWS * DIM * 2);             // 1 MB
    float* cpart = (float*)(ws + 2 * (size_t)NROWS * DIM * 2
                               + (size_t)NPART * NROWS * 4);

    normalize_kernel<<<NROWS / 4, 256, 0, stream>>>(z_i, z_j, zn, pk);
    simloss_kernel<<<(NROWS / ROWS_PER_BLOCK) * CS_COUNT, 256, 0, stream>>>(pk, part);
    rowloss_kernel<<<NROWS / 32, 256, 0, stream>>>(zn, part, cpart);
    final_kernel<<<1, 256, 0, stream>>>(cpart, out);
}

// Round 5
// 60.210 us; speedup vs baseline: 2.9322x; 1.0846x over previous
//
#include <hip/hip_runtime.h>
#include <hip/hip_bf16.h>
#include <math.h>

#define BATCH 4096
#define NROWS 8192
#define DIM 256
#define NP 64                         // 128-row panels
#define NBLK (NP * (NP + 1) / 2)      // 2080 triangular blocks

// zn scale c with c^2 = 2*log2(e): sim_scaled = c^2*cos = 2*log2e*cos,
// so exp2(sim_scaled) = e^{2 cos} directly.
#define ZN_SCALE 1.698643600577466f   // sqrt(2.8853900817779268)
#define LN2F 0.6931471805599453f

typedef __attribute__((ext_vector_type(4))) float f32x4;
typedef __attribute__((ext_vector_type(8))) short short8;

#if defined(__has_builtin)
#if __has_builtin(__builtin_amdgcn_exp2f)
#define EXP2F(x) __builtin_amdgcn_exp2f(x)
#endif
#endif
#ifndef EXP2F
#define EXP2F(x) __expf(LN2F * (x))
#endif

static __device__ __forceinline__ unsigned short f2bf(float x) {
    __hip_bfloat16 h = __float2bfloat16(x);
    return *reinterpret_cast<unsigned short*>(&h);
}
static __device__ __forceinline__ float bf2f(unsigned short u) {
    union { unsigned int i; float f; } x;
    x.i = ((unsigned int)u) << 16;
    return x.f;
}

// ---------------------------------------------------------------------------
// Kernel A: concat + L2-normalize + scale, write row-major (zn) AND
// MFMA-fragment-packed (pk) layouts.
// pk: element (row r, dim e) lives at granule g*8 + (e&7), where
//     g = ((r>>4)*8 + (e>>5))*64 + ((e&31)>>3)*16 + (r&15)
// i.e. one 1KB granule-row per (16-row x 32-k) MFMA fragment, in lane order.
// ---------------------------------------------------------------------------
__global__ void normalize_kernel(const float* __restrict__ z_i,
                                 const float* __restrict__ z_j,
                                 unsigned short* __restrict__ zn,
                                 unsigned short* __restrict__ pk) {
    int wid  = (blockIdx.x * blockDim.x + threadIdx.x) >> 6;   // row
    int lane = threadIdx.x & 63;
    if (wid >= NROWS) return;
    const float* src = (wid < BATCH) ? (z_i + (size_t)wid * DIM)
                                     : (z_j + (size_t)(wid - BATCH) * DIM);
    float4 v = reinterpret_cast<const float4*>(src)[lane];
    float ss = v.x * v.x + v.y * v.y + v.z * v.z + v.w * v.w;
#pragma unroll
    for (int m = 1; m < 64; m <<= 1) ss += __shfl_xor(ss, m);
    float inv = ZN_SCALE / fmaxf(sqrtf(ss), 1e-8f);
    ushort4 o;
    o.x = f2bf(v.x * inv);
    o.y = f2bf(v.y * inv);
    o.z = f2bf(v.z * inv);
    o.w = f2bf(v.w * inv);
    reinterpret_cast<ushort4*>(zn + (size_t)wid * DIM)[lane] = o;
    size_t g = ((size_t)(wid >> 4) * 8 + (lane >> 3)) * 64
             + ((lane & 7) >> 1) * 16 + (wid & 15);
    *reinterpret_cast<ushort4*>(pk + g * 8 + (lane & 1) * 4) = o;
}

// ---------------------------------------------------------------------------
// Kernel B: symmetric fused sim-GEMM + sum-of-exp.
// Grid: 2080 blocks = upper-triangle panel pairs (p,q), p<=q, 128x128 tiles.
// Block = 4 waves (2x2): wave (wr,wc) owns the 64x64 quadrant.
// K-loop: 4 steps of BK=64; A(panel p)[128x64] + B(panel q)[128x64] staged
// via global_load_lds (double-buffered, 64 KB LDS).
// Epilogue (once per block): exp2 of all 16 fragments; row-sums -> piece q of
// panel-p rows; col-sums (p!=q only) -> piece p of panel-q rows (symmetry).
// part layout: [NROWS][NP] (transposed) for coalesced rowloss reads.
// ---------------------------------------------------------------------------
typedef const __attribute__((address_space(1))) unsigned int g_u32;
typedef __attribute__((address_space(3))) unsigned int l_u32;

__device__ __forceinline__ void stage_step(const char* __restrict__ pkb,
                                           char* lds, int wave, int lane,
                                           int p, int q, int ks, int buf) {
#pragma unroll
    for (int i = 0; i < 8; ++i) {
        int id  = wave * 8 + i;
        int isB = id >> 4;               // waves 0,1 stage A(p); 2,3 stage B(q)
        int rtl = (id >> 1) & 7;         // local row-tile 0..7
        int kf  = id & 1;                // k-frag within BK=64
        int rtbase = (isB ? q : p) * 8;
        size_t grow = (size_t)(rtbase + rtl) * 8 + ks * 2 + kf;
        const char* src = pkb + grow * 1024 + (size_t)lane * 16;
        char* dst = lds + buf * 32768 + isB * 16384 + (rtl * 2 + kf) * 1024;
        __builtin_amdgcn_global_load_lds((g_u32*)src, (l_u32*)dst, 16, 0, 0);
    }
}

__global__ __launch_bounds__(256, 2)
void simloss_kernel(const unsigned short* __restrict__ pk,
                    float* __restrict__ part /* [NROWS][NP] */) {
    __shared__ __attribute__((aligned(16))) unsigned char lds[65536];
    int wave = threadIdx.x >> 6;
    int lane = threadIdx.x & 63;
    int lr = lane & 15;                  // fragment col
    int lk = lane >> 4;                  // fragment row group
    // triangular unrank: blockIdx.x -> (p, q), p <= q
    int t = blockIdx.x;
    int p = (int)((129.0 - sqrt(16641.0 - 8.0 * (double)t)) * 0.5);
    p = p < 0 ? 0 : (p > 63 ? 63 : p);
    while (p > 0 && t < p * (129 - p) / 2) --p;
    while (p < 63 && t >= (p + 1) * (128 - p) / 2) ++p;
    int q = p + (t - p * (129 - p) / 2);

    int wr = wave >> 1, wc = wave & 1;
    int wr4 = wr * 4, wc4 = wc * 4;
    int R0 = p * 128 + wr * 64;
    int C0 = q * 128 + wc * 64;
    const char* pkb = (const char*)pk;

    f32x4 acc[4][4];
#pragma unroll
    for (int m = 0; m < 4; ++m)
#pragma unroll
        for (int n = 0; n < 4; ++n) acc[m][n] = (f32x4){0.f, 0.f, 0.f, 0.f};

    stage_step(pkb, (char*)lds, wave, lane, p, q, 0, 0);

#pragma unroll 1
    for (int s = 0; s < 4; ++s) {
        int buf = s & 1;
        if (s < 3) {
            stage_step(pkb, (char*)lds, wave, lane, p, q, s + 1, buf ^ 1);
            asm volatile("s_waitcnt vmcnt(8)" ::: "memory");
        } else {
            asm volatile("s_waitcnt vmcnt(0)" ::: "memory");
        }
        __builtin_amdgcn_s_barrier();

        const unsigned short* Ab = (const unsigned short*)(lds + buf * 32768);
        const unsigned short* Bb = (const unsigned short*)(lds + buf * 32768 + 16384);
#pragma unroll
        for (int kf = 0; kf < 2; ++kf) {
            short8 a[4], b[4];
#pragma unroll
            for (int m = 0; m < 4; ++m)
                a[m] = *(const short8*)(Ab + ((wr4 + m) * 2 + kf) * 512 + lane * 8);
#pragma unroll
            for (int n = 0; n < 4; ++n)
                b[n] = *(const short8*)(Bb + ((wc4 + n) * 2 + kf) * 512 + lane * 8);
#pragma unroll
            for (int m = 0; m < 4; ++m)
#pragma unroll
                for (int n = 0; n < 4; ++n)
                    acc[m][n] = __builtin_amdgcn_mfma_f32_16x16x32_bf16(
                        a[m], b[n], acc[m][n], 0, 0, 0);
        }
        asm volatile("" ::: "memory");
        __builtin_amdgcn_s_barrier();
    }

    // ---- epilogue: exp2, diag-zero, row partials + (p!=q) col partials ----
    float dacc[4][4];
#pragma unroll
    for (int m = 0; m < 4; ++m)
#pragma unroll
        for (int j = 0; j < 4; ++j) dacc[m][j] = 0.f;
    float cacc[4] = {0.f, 0.f, 0.f, 0.f};

#pragma unroll
    for (int m = 0; m < 4; ++m) {
        int gr = R0 + m * 16;
#pragma unroll
        for (int n = 0; n < 4; ++n) {
            int gc = C0 + n * 16;
            bool diagf = (gr == gc);      // uniform per fragment
            float cs_ = 0.f;
#pragma unroll
            for (int j = 0; j < 4; ++j) {
                float e = EXP2F(acc[m][n][j]);
                if (diagf && lr == lk * 4 + j) e = 0.0f;  // exclude diagonal
                dacc[m][j] += e;
                cs_ += e;
            }
            cacc[n] += cs_;
        }
    }

    // cross-lane + cross-wave reduction via LDS (staging buffer is dead now)
    float* red = (float*)lds;            // [0..255] rows, [256..511] cols
#pragma unroll
    for (int m = 0; m < 4; ++m)
#pragma unroll
        for (int j = 0; j < 4; ++j) {
            float v = dacc[m][j];
            v += __shfl_xor(v, 1);
            v += __shfl_xor(v, 2);
            v += __shfl_xor(v, 4);
            v += __shfl_xor(v, 8);
            if (lr == 0) red[wave * 64 + m * 16 + lk * 4 + j] = v;
        }
    if (p != q) {
#pragma unroll
        for (int n = 0; n < 4; ++n) {
            float c = cacc[n];
            c += __shfl_xor(c, 16);
            c += __shfl_xor(c, 32);
            if (lk == 0) red[256 + wave * 64 + n * 16 + lr] = c;
        }
    }
    __syncthreads();

    int tid = threadIdx.x;
    if (tid < 128) {                     // row pieces: piece q of panel-p rows
        int wrh = tid >> 6, loc = tid & 63;
        float v = red[(wrh * 2 + 0) * 64 + loc] + red[(wrh * 2 + 1) * 64 + loc];
        part[(size_t)(p * 128 + tid) * NP + q] = v;
    } else if (p != q) {                 // col pieces: piece p of panel-q rows
        int i2 = tid - 128;
        int wch = i2 >> 6, loc = i2 & 63;
        float v = red[256 + wch * 64 + loc] + red[256 + (2 + wch) * 64 + loc];
        part[(size_t)(q * 128 + i2) * NP + p] = v;
    }
}

// ---------------------------------------------------------------------------
// Kernel C: per-row loss: log(sum of 64 pieces) - pos_dot*ln2
// (zn is scaled so dot = 2*log2e*cos; 2*cos = dot*ln2)
// ---------------------------------------------------------------------------
__global__ void rowloss_kernel(const unsigned short* __restrict__ zn,
                               const float* __restrict__ part,
                               float* __restrict__ cpart) {
    int wave = threadIdx.x >> 6;
    int lane = threadIdx.x & 63;
    float wsum = 0.0f;
#pragma unroll 1
    for (int it = 0; it < 8; ++it) {
        int r = blockIdx.x * 32 + wave * 8 + it;
        ushort4 za = reinterpret_cast<const ushort4*>(zn + (size_t)r * DIM)[lane];
        ushort4 zb = reinterpret_cast<const ushort4*>(zn + (size_t)(r ^ BATCH) * DIM)[lane];
        float dot = bf2f(za.x) * bf2f(zb.x) + bf2f(za.y) * bf2f(zb.y) +
                    bf2f(za.z) * bf2f(zb.z) + bf2f(za.w) * bf2f(zb.w);
#pragma unroll
        for (int m = 1; m < 64; m <<= 1) dot += __shfl_xor(dot, m);
        float den = part[(size_t)r * NP + lane];
#pragma unroll
        for (int m = 1; m < 64; m <<= 1) den += __shfl_xor(den, m);
        if (lane == 0) wsum += logf(den) - dot * LN2F;
    }
    __shared__ float red[4];
    if (lane == 0) red[wave] = wsum;
    __syncthreads();
    if (threadIdx.x == 0)
        cpart[blockIdx.x] = red[0] + red[1] + red[2] + red[3];
}

// ---------------------------------------------------------------------------
// Kernel D: final reduction of 256 block partials -> scalar loss / n
// ---------------------------------------------------------------------------
__global__ void final_kernel(const float* __restrict__ cpart,
                             float* __restrict__ out) {
    int lane = threadIdx.x & 63;
    int wave = threadIdx.x >> 6;
    double v = (double)cpart[threadIdx.x];
#pragma unroll
    for (int m = 1; m < 64; m <<= 1) v += __shfl_xor(v, m);
    __shared__ double red[4];
    if (lane == 0) red[wave] = v;
    __syncthreads();
    if (threadIdx.x == 0)
        out[0] = (float)((red[0] + red[1] + red[2] + red[3]) / (double)NROWS);
}

// ---------------------------------------------------------------------------
extern "C" void kernel_launch(void* const* d_in, const int* in_sizes, int n_in,
                              void* d_out, int out_size, void* d_ws, size_t ws_size,
                              hipStream_t stream) {
    const float* z_i = (const float*)d_in[0];
    const float* z_j = (const float*)d_in[1];
    float* out = (float*)d_out;
    char* ws = (char*)d_ws;

    unsigned short* zn = (unsigned short*)ws;                              // 4 MB
    unsigned short* pk = (unsigned short*)(ws + (size_t)NROWS * DIM * 2);  // 4 MB
    float* part  = (float*)(ws + 2 * (size_t)NROWS * DIM * 2);             // 2 MB
    float* cpart = (float*)(ws + 2 * (size_t)NROWS * DIM * 2
                               + (size_t)NROWS * NP * 4);

    normalize_kernel<<<NROWS / 4, 256, 0, stream>>>(z_i, z_j, zn, pk);
    simloss_kernel<<<NBLK, 256, 0, stream>>>(pk, part);
    rowloss_kernel<<<NROWS / 32, 256, 0, stream>>>(zn, part, cpart);
    final_kernel<<<1, 256, 0, stream>>>(cpart, out);
}